// Round 4
// baseline (219.971 us; speedup 1.0000x reference)
//
#include <hip/hip_runtime.h>
#include <cmath>

#define Nn    8192
#define INF_  512
#define OUTF  64

typedef __attribute__((ext_vector_type(4))) int   i4;
typedef __attribute__((ext_vector_type(4))) float f4v;
typedef __attribute__((ext_vector_type(8))) short s8;
typedef __attribute__((ext_vector_type(4))) float f32x4;

__device__ __forceinline__ float lrelu(float v) { return fmaxf(v, 0.2f * v); }

__device__ __forceinline__ unsigned int f2bf(float f) {
    unsigned int u = __float_as_uint(f);
    u = (u + 0x7FFFu + ((u >> 16) & 1u)) >> 16;
    return u;
}

// ---------------------------------------------------------------------------
// k0q: q1 = W @ a[:64], q2 = W @ a[64:].  1 block x 512 threads.
// ---------------------------------------------------------------------------
__global__ __launch_bounds__(512) void k0q(
    const float* __restrict__ W, const float* __restrict__ a,
    float* __restrict__ q1, float* __restrict__ q2)
{
    const int k = threadIdx.x;
    const float* __restrict__ wr = W + (size_t)k * OUTF;
    float s1 = 0.f, s2 = 0.f;
    #pragma unroll
    for (int c = 0; c < 16; ++c) {
        const f4v wv = ((const f4v*)wr)[c];
        const f4v a1 = ((const f4v*)a)[c];
        const f4v a2 = ((const f4v*)(a + OUTF))[c];
        s1 += wv.x * a1.x + wv.y * a1.y + wv.z * a1.z + wv.w * a1.w;
        s2 += wv.x * a2.x + wv.y * a2.y + wv.z * a2.z + wv.w * a2.w;
    }
    q1[k] = s1; q2[k] = s2;
}

// ---------------------------------------------------------------------------
// k0r: Wh1 = x @ q1, Wh2 = x @ q2.  Wave per row; grid N/4, 256 thr.
// ---------------------------------------------------------------------------
__global__ __launch_bounds__(256) void k0r(
    const float* __restrict__ x, const float* __restrict__ q1,
    const float* __restrict__ q2, float* __restrict__ Wh1,
    float* __restrict__ Wh2)
{
    const int lane = threadIdx.x & 63;
    const int wv   = threadIdx.x >> 6;
    const int row  = blockIdx.x * 4 + wv;
    const float* __restrict__ xr = x + (size_t)row * INF_;

    const f4v x0 = ((const f4v*)xr)[lane * 2];
    const f4v x1 = ((const f4v*)xr)[lane * 2 + 1];
    const f4v p0 = ((const f4v*)q1)[lane * 2];
    const f4v p1 = ((const f4v*)q1)[lane * 2 + 1];
    const f4v r0 = ((const f4v*)q2)[lane * 2];
    const f4v r1 = ((const f4v*)q2)[lane * 2 + 1];

    float s1 = x0.x * p0.x + x0.y * p0.y + x0.z * p0.z + x0.w * p0.w
             + x1.x * p1.x + x1.y * p1.y + x1.z * p1.z + x1.w * p1.w;
    float s2 = x0.x * r0.x + x0.y * r0.y + x0.z * r0.z + x0.w * r0.w
             + x1.x * r1.x + x1.y * r1.y + x1.z * r1.z + x1.w * r1.w;
    #pragma unroll
    for (int off = 32; off; off >>= 1) {
        s1 += __shfl_xor(s1, off);
        s2 += __shfl_xor(s2, off);
    }
    if (lane == 0) { Wh1[row] = s1; Wh2[row] = s2; }
}

// ---------------------------------------------------------------------------
// k12: fused. blockIdx%5==0 -> GEMM block (Wh = x@W -> WhT bf16 [64][N]);
// else -> adjacency-scan block (bitmask, row max, 1/S).
// Interleaved 1:4 so both kinds are co-resident; the HBM-bound scan hides
// the VALU-bound GEMM.
// ---------------------------------------------------------------------------
__global__ __launch_bounds__(256) void k12(
    const float* __restrict__ x, const float* __restrict__ W,
    const int* __restrict__ adj, const float* __restrict__ Wh1,
    const float* __restrict__ Wh2, unsigned short* __restrict__ WhT,
    unsigned long long* __restrict__ bm_g, float* __restrict__ m_g,
    float* __restrict__ is_g)
{
    __shared__ unsigned long long bm[4][Nn / 64];   // 4 KB (scan path only)
    const int t = threadIdx.x;
    const int g = blockIdx.x / 5;
    const int r = blockIdx.x % 5;

    if (r == 0) {
        // ---------------- GEMM block ----------------
        const int row = g * 16 + (t >> 4);
        const int cg  = (t & 15) << 2;
        const float* __restrict__ xr = x + (size_t)row * INF_;
        float4 acc = make_float4(0.f, 0.f, 0.f, 0.f);
        for (int k = 0; k < INF_; k += 4) {
            const float4 xv = *(const float4*)(xr + k);
            const float* wp = W + (size_t)k * OUTF + cg;
            const float4 w0 = *(const float4*)(wp);
            const float4 w1 = *(const float4*)(wp + OUTF);
            const float4 w2 = *(const float4*)(wp + 2 * OUTF);
            const float4 w3 = *(const float4*)(wp + 3 * OUTF);
            acc.x += xv.x * w0.x + xv.y * w1.x + xv.z * w2.x + xv.w * w3.x;
            acc.y += xv.x * w0.y + xv.y * w1.y + xv.z * w2.y + xv.w * w3.y;
            acc.z += xv.x * w0.z + xv.y * w1.z + xv.z * w2.z + xv.w * w3.z;
            acc.w += xv.x * w0.w + xv.y * w1.w + xv.z * w2.w + xv.w * w3.w;
        }
        WhT[(size_t)(cg + 0) * Nn + row] = (unsigned short)f2bf(acc.x);
        WhT[(size_t)(cg + 1) * Nn + row] = (unsigned short)f2bf(acc.y);
        WhT[(size_t)(cg + 2) * Nn + row] = (unsigned short)f2bf(acc.z);
        WhT[(size_t)(cg + 3) * Nn + row] = (unsigned short)f2bf(acc.w);
        return;
    }

    // ---------------- scan block ----------------
    const int lane = t & 63;
    const int wv   = t >> 6;
    const int row  = (g * 4 + (r - 1)) * 4 + wv;
    const int* __restrict__ arow = adj + (size_t)row * Nn;

    float mx = -INFINITY;
    for (int jb = 0; jb < Nn; jb += 256) {
        const i4  av = __builtin_nontemporal_load((const i4*)(arow + jb) + lane);
        const f4v w4 = *((const f4v*)(Wh2 + jb) + lane);
        const int nib = (av.x != 0 ? 1 : 0) | (av.y != 0 ? 2 : 0)
                      | (av.z != 0 ? 4 : 0) | (av.w != 0 ? 8 : 0);
        const float m0 = av.x ? w4.x : -INFINITY;
        const float m1 = av.y ? w4.y : -INFINITY;
        const float m2 = av.z ? w4.z : -INFINITY;
        const float m3 = av.w ? w4.w : -INFINITY;
        mx = fmaxf(mx, fmaxf(fmaxf(m0, m1), fmaxf(m2, m3)));

        unsigned long long part = (unsigned long long)nib << ((lane & 15) * 4);
        part |= __shfl_xor(part, 1);
        part |= __shfl_xor(part, 2);
        part |= __shfl_xor(part, 4);
        part |= __shfl_xor(part, 8);
        if ((lane & 15) == 0) bm[wv][(jb >> 6) + (lane >> 4)] = part;
    }
    #pragma unroll
    for (int off = 32; off; off >>= 1) mx = fmaxf(mx, __shfl_xor(mx, off));

    __syncthreads();

    const float h1 = Wh1[row];
    const float K  = lrelu(h1 + mx);
    float S = 0.0f;
    for (int w = 0; w < Nn / 64; ++w) {
        const unsigned long long b = bm[wv][w];
        const float e  = lrelu(h1 + Wh2[w * 64 + lane]);
        const float ex = __expf(e - K);
        if ((b >> lane) & 1ull) S += ex;
    }
    #pragma unroll
    for (int off = 32; off; off >>= 1) S += __shfl_xor(S, off);
    if (lane == 0) { m_g[row] = K; is_g[row] = 1.0f / S; }

    unsigned long long* __restrict__ dst = bm_g + (size_t)row * (Nn / 64);
    #pragma unroll
    for (int w = lane; w < Nn / 64; w += 64) dst[w] = bm[wv][w];
}

// ---------------------------------------------------------------------------
// k2b: att materialization (f32 global) + bf16 LDS tile + MFMA PV + ELU.
// 512 thr = 8 waves; 16 rows/block; grid 512; chunk = 256 js (32 barriers).
// Producer: wave w -> rows {2w,2w+1}, lane -> 4 js (f4 stores, b64 LDS).
// LDS [16][512B] XOR-swizzled (byte ^= (row&7)<<4) -> 2-way (free).
// PV: wave w -> coltile ct=w&3, khalf kh=w>>2, 4x mfma_16x16x32_bf16/chunk.
// ---------------------------------------------------------------------------
__global__ __launch_bounds__(512) void k2b_pv(
    const unsigned short* __restrict__ WhT, const float* __restrict__ Wh1,
    const float* __restrict__ Wh2, const unsigned long long* __restrict__ bm_g,
    const float* __restrict__ m_g, const float* __restrict__ is_g,
    float* __restrict__ outp, float* __restrict__ att)
{
    __shared__ alignas(16) unsigned short att_t[2][16 * 256];  // 16 KB
    __shared__ float red[4][16][16];                           // 4 KB

    const int t    = threadIdx.x;
    const int lane = t & 63;
    const int w    = t >> 6;
    const int row0 = blockIdx.x * 16;

    const int rA = 2 * w, rB = 2 * w + 1;
    const float h1A = Wh1[row0 + rA], mA = m_g[row0 + rA], isA = is_g[row0 + rA];
    const float h1B = Wh1[row0 + rB], mB = m_g[row0 + rB], isB = is_g[row0 + rB];
    const unsigned long long* __restrict__ bmA = bm_g + (size_t)(row0 + rA) * (Nn / 64);
    const unsigned long long* __restrict__ bmB = bm_g + (size_t)(row0 + rB) * (Nn / 64);

    const int ct = w & 3;    // col tile (16 cols)
    const int kh = w >> 2;   // k half (4 of 8 ksteps per chunk)
    f32x4 acc = {0.f, 0.f, 0.f, 0.f};

    const int bit0 = (lane * 4) & 63;
    const int wsub = lane >> 4;

    auto produce = [&](int c, int bf) {
        const int jb = c * 256;
        const f4v w2 = ((const f4v*)(Wh2 + jb))[lane];
        const int wi = (jb >> 6) + wsub;
        {
            const unsigned long long bA = bmA[wi];
            const float v0 = ((bA >> bit0) & 1ull)       ? __expf(lrelu(h1A + w2.x) - mA) * isA : 0.f;
            const float v1 = ((bA >> (bit0 + 1)) & 1ull) ? __expf(lrelu(h1A + w2.y) - mA) * isA : 0.f;
            const float v2 = ((bA >> (bit0 + 2)) & 1ull) ? __expf(lrelu(h1A + w2.z) - mA) * isA : 0.f;
            const float v3 = ((bA >> (bit0 + 3)) & 1ull) ? __expf(lrelu(h1A + w2.w) - mA) * isA : 0.f;
            f4v st; st.x = v0; st.y = v1; st.z = v2; st.w = v3;
            __builtin_nontemporal_store(st, (f4v*)(att + (size_t)(row0 + rA) * Nn + jb) + lane);
            const unsigned long long pk =
                (unsigned long long)(f2bf(v0) | (f2bf(v1) << 16))
              | ((unsigned long long)(f2bf(v2) | (f2bf(v3) << 16)) << 32);
            int byte = rA * 512 + lane * 8;  byte ^= (rA & 7) << 4;
            *(unsigned long long*)((char*)att_t[bf] + byte) = pk;
        }
        {
            const unsigned long long bB = bmB[wi];
            const float v0 = ((bB >> bit0) & 1ull)       ? __expf(lrelu(h1B + w2.x) - mB) * isB : 0.f;
            const float v1 = ((bB >> (bit0 + 1)) & 1ull) ? __expf(lrelu(h1B + w2.y) - mB) * isB : 0.f;
            const float v2 = ((bB >> (bit0 + 2)) & 1ull) ? __expf(lrelu(h1B + w2.z) - mB) * isB : 0.f;
            const float v3 = ((bB >> (bit0 + 3)) & 1ull) ? __expf(lrelu(h1B + w2.w) - mB) * isB : 0.f;
            f4v st; st.x = v0; st.y = v1; st.z = v2; st.w = v3;
            __builtin_nontemporal_store(st, (f4v*)(att + (size_t)(row0 + rB) * Nn + jb) + lane);
            const unsigned long long pk =
                (unsigned long long)(f2bf(v0) | (f2bf(v1) << 16))
              | ((unsigned long long)(f2bf(v2) | (f2bf(v3) << 16)) << 32);
            int byte = rB * 512 + lane * 8;  byte ^= (rB & 7) << 4;
            *(unsigned long long*)((char*)att_t[bf] + byte) = pk;
        }
    };

    const int arow = lane & 15;
    const int agrp = lane >> 4;
    auto domfma = [&](int c, int bf) {
        const int jb = c * 256;
        #pragma unroll
        for (int s = 0; s < 4; ++s) {
            const int ks = kh * 4 + s;
            int byte = arow * 512 + ks * 64 + agrp * 16;
            byte ^= (arow & 7) << 4;
            const s8 afrag = *(const s8*)((char*)att_t[bf] + byte);
            const s8 bfrag = *(const s8*)(WhT + (size_t)(ct * 16 + arow) * Nn
                                          + jb + ks * 32 + agrp * 8);
            acc = __builtin_amdgcn_mfma_f32_16x16x32_bf16(afrag, bfrag, acc, 0, 0, 0);
        }
    };

    produce(0, 0);
    __syncthreads();
    for (int c = 0; c < Nn / 256 - 1; ++c) {
        produce(c + 1, (c + 1) & 1);
        domfma(c, c & 1);
        __syncthreads();
    }
    domfma(Nn / 256 - 1, (Nn / 256 - 1) & 1);

    __syncthreads();
    if (kh == 1) {
        #pragma unroll
        for (int q = 0; q < 4; ++q) red[ct][agrp * 4 + q][arow] = acc[q];
    }
    __syncthreads();
    if (kh == 0) {
        #pragma unroll
        for (int q = 0; q < 4; ++q) {
            float v = acc[q] + red[ct][agrp * 4 + q][arow];
            v = v > 0.f ? v : expm1f(v);
            outp[(size_t)(row0 + agrp * 4 + q) * OUTF + ct * 16 + arow] = v;
        }
    }
}

// ---------------------------------------------------------------------------
extern "C" void kernel_launch(void* const* d_in, const int* in_sizes, int n_in,
                              void* d_out, int out_size, void* d_ws, size_t ws_size,
                              hipStream_t stream)
{
    const float* x   = (const float*)d_in[0];
    const int*   adj = (const int*)d_in[1];
    const float* W   = (const float*)d_in[2];
    const float* a   = (const float*)d_in[3];

    float* outp = (float*)d_out;                       // [N, 64]
    float* att  = outp + (size_t)Nn * OUTF;            // [N, N]

    // workspace layout (~9.2 MB)
    float* Wh1 = (float*)d_ws;                          // 32 KB
    float* Wh2 = Wh1 + Nn;                              // 32 KB
    float* m_g = Wh2 + Nn;                              // 32 KB
    float* is_g = m_g + Nn;                             // 32 KB
    float* q1  = is_g + Nn;                             // 2 KB
    float* q2  = q1 + INF_;                             // 2 KB
    unsigned short* WhT = (unsigned short*)(q2 + INF_); // 1 MB bf16 [64][N]
    unsigned long long* bm_g = (unsigned long long*)(WhT + (size_t)OUTF * Nn); // 8 MB

    hipLaunchKernelGGL(k0q, dim3(1),        dim3(512), 0, stream, W, a, q1, q2);
    hipLaunchKernelGGL(k0r, dim3(Nn / 4),   dim3(256), 0, stream, x, q1, q2, Wh1, Wh2);
    hipLaunchKernelGGL(k12, dim3(2560),     dim3(256), 0, stream,
                       x, W, adj, Wh1, Wh2, WhT, bm_g, m_g, is_g);
    hipLaunchKernelGGL(k2b_pv, dim3(Nn / 16), dim3(512), 0, stream,
                       WhT, Wh1, Wh2, bm_g, m_g, is_g, outp, att);
}

// Round 5
// 205.403 us; speedup vs baseline: 1.0709x; 1.0709x over previous
//
#include <hip/hip_runtime.h>
#include <cmath>

#define Nn    8192
#define INF_  512
#define OUTF  64

typedef __attribute__((ext_vector_type(4))) int   i4;
typedef __attribute__((ext_vector_type(4))) float f4v;
typedef __attribute__((ext_vector_type(8))) short s8;
typedef __attribute__((ext_vector_type(4))) float f32x4;
typedef unsigned long long u64;

__device__ __forceinline__ float lrelu(float v) { return fmaxf(v, 0.2f * v); }

__device__ __forceinline__ unsigned int f2bf(float f) {
    unsigned int u = __float_as_uint(f);
    u = (u + 0x7FFFu + ((u >> 16) & 1u)) >> 16;
    return u;
}

// ---------------------------------------------------------------------------
// k1: Wh = x @ W (regs) -> WhT bf16 [64][N];  Wh1 = Wh@a[:64]; Wh2 = Wh@a[64:]
// 256 thr = 16 rows x 16 colgroups(4).  Grid N/16 = 512.
// ---------------------------------------------------------------------------
__global__ __launch_bounds__(256) void k1_wh(
    const float* __restrict__ x, const float* __restrict__ W,
    const float* __restrict__ a, unsigned short* __restrict__ WhT,
    float* __restrict__ Wh1, float* __restrict__ Wh2)
{
    const int t   = threadIdx.x;
    const int row = blockIdx.x * 16 + (t >> 4);
    const int cg  = (t & 15) << 2;
    const float* __restrict__ xr = x + (size_t)row * INF_;

    float4 acc = make_float4(0.f, 0.f, 0.f, 0.f);
    for (int k = 0; k < INF_; k += 4) {
        const float4 xv = *(const float4*)(xr + k);
        const float* wp = W + (size_t)k * OUTF + cg;
        const float4 w0 = *(const float4*)(wp);
        const float4 w1 = *(const float4*)(wp + OUTF);
        const float4 w2 = *(const float4*)(wp + 2 * OUTF);
        const float4 w3 = *(const float4*)(wp + 3 * OUTF);
        acc.x += xv.x * w0.x + xv.y * w1.x + xv.z * w2.x + xv.w * w3.x;
        acc.y += xv.x * w0.y + xv.y * w1.y + xv.z * w2.y + xv.w * w3.y;
        acc.z += xv.x * w0.z + xv.y * w1.z + xv.z * w2.z + xv.w * w3.z;
        acc.w += xv.x * w0.w + xv.y * w1.w + xv.z * w2.w + xv.w * w3.w;
    }
    WhT[(size_t)(cg + 0) * Nn + row] = (unsigned short)f2bf(acc.x);
    WhT[(size_t)(cg + 1) * Nn + row] = (unsigned short)f2bf(acc.y);
    WhT[(size_t)(cg + 2) * Nn + row] = (unsigned short)f2bf(acc.z);
    WhT[(size_t)(cg + 3) * Nn + row] = (unsigned short)f2bf(acc.w);

    float p1 = acc.x * a[cg]        + acc.y * a[cg + 1]
             + acc.z * a[cg + 2]    + acc.w * a[cg + 3];
    float p2 = acc.x * a[OUTF + cg]     + acc.y * a[OUTF + cg + 1]
             + acc.z * a[OUTF + cg + 2] + acc.w * a[OUTF + cg + 3];
    #pragma unroll
    for (int off = 8; off; off >>= 1) {
        p1 += __shfl_xor(p1, off);
        p2 += __shfl_xor(p2, off);
    }
    if ((t & 15) == 0) { Wh1[row] = p1; Wh2[row] = p2; }
}

// ---------------------------------------------------------------------------
// k2: FUSED per 16-row block (512 thr = 8 waves, wave w -> rows {2w,2w+1}):
//  Phase A: scan own adj slab (dwordx4 nontemporal), nibble->u64 via
//           4x shfl_xor OR, bitmask to LDS bm[16][128]; masked max of Wh2
//           (monotone-LeakyReLU trick) -> K; exp-sum S from LDS mask.
//           Row constants stay in registers (butterfly leaves them lane-wide).
//  Phase B: per 256-j chunk: att = bit ? exp(lrelu(h1+w2)-K)/S : 0;
//           f32 nontemporal global store + bf16 XOR-swizzled LDS tile;
//           MFMA PV (wave w: coltile ct=w&3, khalf kh=w>>2,
//           4x mfma_f32_16x16x32_bf16 per chunk, double-buffered).
//  Epilogue: kh-pair reduce via LDS, ELU, store out.
// ---------------------------------------------------------------------------
__global__ __launch_bounds__(512) void k2_fused(
    const int* __restrict__ adj, const unsigned short* __restrict__ WhT,
    const float* __restrict__ Wh1, const float* __restrict__ Wh2,
    float* __restrict__ outp, float* __restrict__ att)
{
    __shared__ alignas(16) u64 bm[16][Nn / 64];                // 16 KB
    __shared__ alignas(16) unsigned short att_t[2][16 * 256];  // 16 KB
    __shared__ float red[4][16][16];                           // 4 KB

    const int t    = threadIdx.x;
    const int lane = t & 63;
    const int w    = t >> 6;
    const int row0 = blockIdx.x * 16;

    const int rA = 2 * w, rB = 2 * w + 1;
    const int rowA = row0 + rA, rowB = row0 + rB;
    const int* __restrict__ arowA = adj + (size_t)rowA * Nn;
    const int* __restrict__ arowB = adj + (size_t)rowB * Nn;

    // ---------------- Phase A: adj scan -> LDS bitmask + masked max ----------
    const int shl = (lane & 15) * 4;
    float mxA = -INFINITY, mxB = -INFINITY;
    for (int jb = 0; jb < Nn; jb += 256) {
        const i4  aA = __builtin_nontemporal_load((const i4*)(arowA + jb) + lane);
        const i4  aB = __builtin_nontemporal_load((const i4*)(arowB + jb) + lane);
        const f4v w4 = *((const f4v*)(Wh2 + jb) + lane);

        const int nibA = (aA.x != 0 ? 1 : 0) | (aA.y != 0 ? 2 : 0)
                       | (aA.z != 0 ? 4 : 0) | (aA.w != 0 ? 8 : 0);
        const int nibB = (aB.x != 0 ? 1 : 0) | (aB.y != 0 ? 2 : 0)
                       | (aB.z != 0 ? 4 : 0) | (aB.w != 0 ? 8 : 0);

        mxA = fmaxf(mxA, fmaxf(fmaxf(aA.x ? w4.x : -INFINITY, aA.y ? w4.y : -INFINITY),
                               fmaxf(aA.z ? w4.z : -INFINITY, aA.w ? w4.w : -INFINITY)));
        mxB = fmaxf(mxB, fmaxf(fmaxf(aB.x ? w4.x : -INFINITY, aB.y ? w4.y : -INFINITY),
                               fmaxf(aB.z ? w4.z : -INFINITY, aB.w ? w4.w : -INFINITY)));

        u64 pA = (u64)nibA << shl;
        u64 pB = (u64)nibB << shl;
        pA |= __shfl_xor(pA, 1); pB |= __shfl_xor(pB, 1);
        pA |= __shfl_xor(pA, 2); pB |= __shfl_xor(pB, 2);
        pA |= __shfl_xor(pA, 4); pB |= __shfl_xor(pB, 4);
        pA |= __shfl_xor(pA, 8); pB |= __shfl_xor(pB, 8);
        if ((lane & 15) == 0) {
            const int wd = (jb >> 6) + (lane >> 4);
            bm[rA][wd] = pA;
            bm[rB][wd] = pB;
        }
    }
    #pragma unroll
    for (int off = 32; off; off >>= 1) {
        mxA = fmaxf(mxA, __shfl_xor(mxA, off));
        mxB = fmaxf(mxB, __shfl_xor(mxB, off));
    }
    const float h1A = Wh1[rowA], h1B = Wh1[rowB];
    const float KA = lrelu(h1A + mxA), KB = lrelu(h1B + mxB);

    __syncthreads();   // bm complete

    float SA = 0.f, SB = 0.f;
    for (int wd = 0; wd < Nn / 64; ++wd) {
        const u64 bA = bm[rA][wd];
        const u64 bB = bm[rB][wd];
        const float w2 = Wh2[wd * 64 + lane];
        const float exA = __expf(lrelu(h1A + w2) - KA);
        const float exB = __expf(lrelu(h1B + w2) - KB);
        if ((bA >> lane) & 1ull) SA += exA;
        if ((bB >> lane) & 1ull) SB += exB;
    }
    #pragma unroll
    for (int off = 32; off; off >>= 1) {
        SA += __shfl_xor(SA, off);
        SB += __shfl_xor(SB, off);
    }
    const float isA = 1.0f / SA, isB = 1.0f / SB;

    // ---------------- Phase B: att materialization + MFMA PV ----------------
    const int ct = w & 3;    // col tile (16 cols)
    const int kh = w >> 2;   // k half (4 of 8 ksteps per chunk)
    f32x4 acc = {0.f, 0.f, 0.f, 0.f};

    const int bit0 = (lane * 4) & 63;
    const int wsub = lane >> 4;

    auto produce = [&](int c, int bf) {
        const int jb = c * 256;
        const f4v w2 = ((const f4v*)(Wh2 + jb))[lane];
        const int wi = (jb >> 6) + wsub;
        {
            const u64 bA = bm[rA][wi];
            const float v0 = ((bA >> bit0) & 1ull)       ? __expf(lrelu(h1A + w2.x) - KA) * isA : 0.f;
            const float v1 = ((bA >> (bit0 + 1)) & 1ull) ? __expf(lrelu(h1A + w2.y) - KA) * isA : 0.f;
            const float v2 = ((bA >> (bit0 + 2)) & 1ull) ? __expf(lrelu(h1A + w2.z) - KA) * isA : 0.f;
            const float v3 = ((bA >> (bit0 + 3)) & 1ull) ? __expf(lrelu(h1A + w2.w) - KA) * isA : 0.f;
            f4v st; st.x = v0; st.y = v1; st.z = v2; st.w = v3;
            __builtin_nontemporal_store(st, (f4v*)(att + (size_t)rowA * Nn + jb) + lane);
            const u64 pk = (u64)(f2bf(v0) | (f2bf(v1) << 16))
                         | ((u64)(f2bf(v2) | (f2bf(v3) << 16)) << 32);
            int byte = rA * 512 + lane * 8;  byte ^= (rA & 7) << 4;
            *(u64*)((char*)att_t[bf] + byte) = pk;
        }
        {
            const u64 bB = bm[rB][wi];
            const float v0 = ((bB >> bit0) & 1ull)       ? __expf(lrelu(h1B + w2.x) - KB) * isB : 0.f;
            const float v1 = ((bB >> (bit0 + 1)) & 1ull) ? __expf(lrelu(h1B + w2.y) - KB) * isB : 0.f;
            const float v2 = ((bB >> (bit0 + 2)) & 1ull) ? __expf(lrelu(h1B + w2.z) - KB) * isB : 0.f;
            const float v3 = ((bB >> (bit0 + 3)) & 1ull) ? __expf(lrelu(h1B + w2.w) - KB) * isB : 0.f;
            f4v st; st.x = v0; st.y = v1; st.z = v2; st.w = v3;
            __builtin_nontemporal_store(st, (f4v*)(att + (size_t)rowB * Nn + jb) + lane);
            const u64 pk = (u64)(f2bf(v0) | (f2bf(v1) << 16))
                         | ((u64)(f2bf(v2) | (f2bf(v3) << 16)) << 32);
            int byte = rB * 512 + lane * 8;  byte ^= (rB & 7) << 4;
            *(u64*)((char*)att_t[bf] + byte) = pk;
        }
    };

    const int arow = lane & 15;
    const int agrp = lane >> 4;
    auto domfma = [&](int c, int bf) {
        const int jb = c * 256;
        #pragma unroll
        for (int s = 0; s < 4; ++s) {
            const int ks = kh * 4 + s;
            int byte = arow * 512 + ks * 64 + agrp * 16;
            byte ^= (arow & 7) << 4;
            const s8 afrag = *(const s8*)((char*)att_t[bf] + byte);
            const s8 bfrag = *(const s8*)(WhT + (size_t)(ct * 16 + arow) * Nn
                                          + jb + ks * 32 + agrp * 8);
            acc = __builtin_amdgcn_mfma_f32_16x16x32_bf16(afrag, bfrag, acc, 0, 0, 0);
        }
    };

    produce(0, 0);
    __syncthreads();
    for (int c = 0; c < Nn / 256 - 1; ++c) {
        produce(c + 1, (c + 1) & 1);
        domfma(c, c & 1);
        __syncthreads();
    }
    domfma(Nn / 256 - 1, (Nn / 256 - 1) & 1);

    __syncthreads();
    if (kh == 1) {
        #pragma unroll
        for (int q = 0; q < 4; ++q) red[ct][agrp * 4 + q][arow] = acc[q];
    }
    __syncthreads();
    if (kh == 0) {
        #pragma unroll
        for (int q = 0; q < 4; ++q) {
            float v = acc[q] + red[ct][agrp * 4 + q][arow];
            v = v > 0.f ? v : expm1f(v);
            outp[(size_t)(row0 + agrp * 4 + q) * OUTF + ct * 16 + arow] = v;
        }
    }
}

// ---------------------------------------------------------------------------
extern "C" void kernel_launch(void* const* d_in, const int* in_sizes, int n_in,
                              void* d_out, int out_size, void* d_ws, size_t ws_size,
                              hipStream_t stream)
{
    const float* x   = (const float*)d_in[0];
    const int*   adj = (const int*)d_in[1];
    const float* W   = (const float*)d_in[2];
    const float* a   = (const float*)d_in[3];

    float* outp = (float*)d_out;                       // [N, 64]
    float* att  = outp + (size_t)Nn * OUTF;            // [N, N]

    // workspace: Wh1, Wh2 (f32), WhT (bf16 [64][N])  ~1.06 MB
    float* Wh1 = (float*)d_ws;
    float* Wh2 = Wh1 + Nn;
    unsigned short* WhT = (unsigned short*)(Wh2 + Nn);

    hipLaunchKernelGGL(k1_wh,    dim3(Nn / 16), dim3(256), 0, stream,
                       x, W, a, WhT, Wh1, Wh2);
    hipLaunchKernelGGL(k2_fused, dim3(Nn / 16), dim3(512), 0, stream,
                       adj, WhT, Wh1, Wh2, outp, att);
}